// Round 1
// baseline (194.742 us; speedup 1.0000x reference)
//
#include <hip/hip_runtime.h>
#include <math.h>

#define BB 8
#define TT 128
#define U1 65
#define UU 64
#define VV 1024

// ---------------- Kernel 1: per-row logsumexp + gather blank/label logprobs ----
// One wave (64 lanes) per row of V=1024 floats; 4 waves (4 rows) per block.
__global__ __launch_bounds__(256) void lse_gather(
    const float* __restrict__ logits, const int* __restrict__ y,
    float* __restrict__ lp_blank, float* __restrict__ lp_label) {
  const int wave = threadIdx.x >> 6;
  const int lane = threadIdx.x & 63;
  const int row  = blockIdx.x * 4 + wave;          // row in [0, B*T*U1)

  const float4* rp = (const float4*)(logits + (size_t)row * VV);
  float4 x0 = rp[lane];
  float4 x1 = rp[lane + 64];
  float4 x2 = rp[lane + 128];
  float4 x3 = rp[lane + 192];

  // decode (b,t,u); issue the label gather early to overlap latency
  const int u = row % U1;
  const int bt = row / U1;           // b*T + t
  const int b = bt / TT;
  const bool have_label = (u < UU);
  float lab_logit = 0.f;
  if (have_label && lane == 0) {
    const int lab = y[b * UU + u];
    lab_logit = logits[(size_t)row * VV + lab];
  }

  float m = fmaxf(fmaxf(fmaxf(x0.x, x0.y), fmaxf(x0.z, x0.w)),
                  fmaxf(fmaxf(x1.x, x1.y), fmaxf(x1.z, x1.w)));
  m = fmaxf(m, fmaxf(fmaxf(fmaxf(x2.x, x2.y), fmaxf(x2.z, x2.w)),
                     fmaxf(fmaxf(x3.x, x3.y), fmaxf(x3.z, x3.w))));
#pragma unroll
  for (int s = 32; s >= 1; s >>= 1) m = fmaxf(m, __shfl_xor(m, s));

  float ss = __expf(x0.x - m) + __expf(x0.y - m) + __expf(x0.z - m) + __expf(x0.w - m)
           + __expf(x1.x - m) + __expf(x1.y - m) + __expf(x1.z - m) + __expf(x1.w - m)
           + __expf(x2.x - m) + __expf(x2.y - m) + __expf(x2.z - m) + __expf(x2.w - m)
           + __expf(x3.x - m) + __expf(x3.y - m) + __expf(x3.z - m) + __expf(x3.w - m);
#pragma unroll
  for (int s = 32; s >= 1; s >>= 1) ss += __shfl_xor(ss, s);

  if (lane == 0) {
    const float lse = m + __logf(ss);
    lp_blank[row] = x0.x - lse;                   // logits[row*V + 0] is x0.x on lane 0
    if (have_label) lp_label[bt * UU + u] = lab_logit - lse;
  }
}

// ---------------- Kernel 2: anti-diagonal alpha recursion, 1 wave per batch ----
__device__ __forceinline__ float lae(float a, float b) {
  const float m = fmaxf(a, b);
  return m + log1pf(__expf(-fabsf(a - b)));
}

__global__ __launch_bounds__(64) void alpha_dp(
    const float* __restrict__ lp_blank, const float* __restrict__ lp_label,
    const int* __restrict__ logit_lens, const int* __restrict__ y_lens,
    float* __restrict__ losses) {
  const int b = blockIdx.x;
  const int lane = threadIdx.x;     // lane == u for u in [0,63]; lane 63 also owns u=64

  __shared__ float s_blank[TT * U1];   // 33280 B
  __shared__ float s_label[TT * UU];   // 32768 B
  {
    const float4* sb = (const float4*)(lp_blank + (size_t)b * TT * U1);
    float4* db = (float4*)s_blank;
    for (int i = lane; i < TT * U1 / 4; i += 64) db[i] = sb[i];
    const float4* sl = (const float4*)(lp_label + (size_t)b * TT * UU);
    float4* dl = (float4*)s_label;
    for (int i = lane; i < TT * UU / 4; i += 64) dl[i] = sl[i];
  }
  __syncthreads();

  const int tEnd = logit_lens[b] - 1;
  const int uEnd = y_lens[b];
  const int dTarget = tEnd + uEnd;

  const int u = lane;
  float a_prev = 0.f;     // this lane's alpha on diagonal d-1 (cell (d-1-u, u))
  float a64_prev = 0.f;   // lane 63 only: alpha at u=64 on diagonal d-1
  float result = 0.f;

  for (int d = 0; d < TT + UU; ++d) {   // d = t+u in [0, 191]
    const float a_left = __shfl_up(a_prev, 1);   // neighbor (u-1) diag d-1 value
    const int t = d - u;
    const bool valid = (t >= 0) && (t < TT);
    float a_cur = a_prev;
    if (valid) {
      if (d == 0)          a_cur = 0.f;
      else if (t == 0)     a_cur = a_left + s_label[u - 1];
      else if (u == 0)     a_cur = a_prev + s_blank[(t - 1) * U1];
      else                 a_cur = lae(a_prev + s_blank[(t - 1) * U1 + u],
                                       a_left + s_label[t * UU + (u - 1)]);
      if (d == dTarget && u == uEnd)
        result = a_cur + s_blank[tEnd * U1 + uEnd];
    }
    if (lane == 63) {       // extra cell u = 64 (reads only lane 63's own state)
      const int t64 = d - 64;
      if (t64 >= 0 && t64 < TT) {
        float a64_cur;
        if (t64 == 0) a64_cur = a_prev + s_label[63];                       // alpha[0][63]+label[0][63]
        else          a64_cur = lae(a64_prev + s_blank[(t64 - 1) * U1 + 64],
                                    a_prev   + s_label[t64 * UU + 63]);
        if (d == dTarget && uEnd == 64)
          result = a64_cur + s_blank[tEnd * U1 + 64];
        a64_prev = a64_cur;
      }
    }
    a_prev = a_cur;
  }

  if (u == uEnd || (lane == 63 && uEnd == 64)) losses[b] = -result;
}

// ---------------- Kernel 3: mean over batch ----------------------------------
__global__ void finalize(const float* __restrict__ losses, float* __restrict__ out) {
  if (threadIdx.x == 0) {
    float s = 0.f;
#pragma unroll
    for (int i = 0; i < BB; ++i) s += losses[i];
    out[0] = s / (float)BB;
  }
}

extern "C" void kernel_launch(void* const* d_in, const int* in_sizes, int n_in,
                              void* d_out, int out_size, void* d_ws, size_t ws_size,
                              hipStream_t stream) {
  const float* logits     = (const float*)d_in[0];
  const int*   logit_lens = (const int*)d_in[1];
  const int*   y          = (const int*)d_in[2];
  const int*   y_lens     = (const int*)d_in[3];
  float* out = (float*)d_out;

  float* lp_blank = (float*)d_ws;                         // B*T*U1 floats
  float* lp_label = lp_blank + BB * TT * U1;              // B*T*U  floats
  float* losses   = lp_label + BB * TT * UU;              // B floats

  const int rows = BB * TT * U1;                          // 66560, divisible by 4
  lse_gather<<<rows / 4, 256, 0, stream>>>(logits, y, lp_blank, lp_label);
  alpha_dp<<<BB, 64, 0, stream>>>(lp_blank, lp_label, logit_lens, y_lens, losses);
  finalize<<<1, 64, 0, stream>>>(losses, out);
}

// Round 2
// 82.585 us; speedup vs baseline: 2.3581x; 2.3581x over previous
//
#include <hip/hip_runtime.h>
#include <math.h>

#define BB 8
#define TT 128
#define U1 65
#define UU 64
#define VV 1024
#define TS 132            // padded column stride: bank=(3u+d)%32 conflict-free, 16B-divisible
#define NEGINF -1e30f

__device__ __forceinline__ float lae(float a, float b) {
  const float m = fmaxf(a, b);
  return m + __logf(1.f + __expf(-fabsf(a - b)));
}

// shfl_up by 1 via DPP wave_shr:1 (VALU latency, no LDS round-trip)
__device__ __forceinline__ float shfl_up1(float x) {
  return __int_as_float(__builtin_amdgcn_update_dpp(
      0, __float_as_int(x), 0x138, 0xf, 0xf, false));
}

// ---------------- Kernel 1: per-row logsumexp + gather blank/label logprobs ----
// One wave per row of V=1024; skips rows the loss provably doesn't read.
__global__ __launch_bounds__(256) void lse_gather(
    const float* __restrict__ logits, const int* __restrict__ y,
    const int* __restrict__ logit_lens, const int* __restrict__ y_lens,
    float* __restrict__ lp_blankT, float* __restrict__ lp_labelT) {
  const int wave = threadIdx.x >> 6;
  const int lane = threadIdx.x & 63;
  const int row  = blockIdx.x * 4 + wave;          // row in [0, B*T*U1)
  const int u  = row % U1;
  const int bt = row / U1;
  const int b  = bt / TT;
  const int t  = bt % TT;
  if (t >= logit_lens[b] || u > y_lens[b]) return; // wave-uniform skip: not needed by DP

  const float4* rp = (const float4*)(logits + (size_t)row * VV);
  float4 x0 = rp[lane];
  float4 x1 = rp[lane + 64];
  float4 x2 = rp[lane + 128];
  float4 x3 = rp[lane + 192];

  const bool have_label = (u < UU);
  float lab_logit = 0.f;
  if (have_label && lane == 0)
    lab_logit = logits[(size_t)row * VV + y[b * UU + u]];  // L1/L2 hit: line just read

  float m = fmaxf(fmaxf(fmaxf(x0.x, x0.y), fmaxf(x0.z, x0.w)),
                  fmaxf(fmaxf(x1.x, x1.y), fmaxf(x1.z, x1.w)));
  m = fmaxf(m, fmaxf(fmaxf(fmaxf(x2.x, x2.y), fmaxf(x2.z, x2.w)),
                     fmaxf(fmaxf(x3.x, x3.y), fmaxf(x3.z, x3.w))));
#pragma unroll
  for (int s = 32; s >= 1; s >>= 1) m = fmaxf(m, __shfl_xor(m, s));

  float ss = __expf(x0.x - m) + __expf(x0.y - m) + __expf(x0.z - m) + __expf(x0.w - m)
           + __expf(x1.x - m) + __expf(x1.y - m) + __expf(x1.z - m) + __expf(x1.w - m)
           + __expf(x2.x - m) + __expf(x2.y - m) + __expf(x2.z - m) + __expf(x2.w - m)
           + __expf(x3.x - m) + __expf(x3.y - m) + __expf(x3.z - m) + __expf(x3.w - m);
#pragma unroll
  for (int s = 32; s >= 1; s >>= 1) ss += __shfl_xor(ss, s);

  if (lane == 0) {
    const float lse = m + __logf(ss);
    lp_blankT[(b * U1 + u) * TS + t] = x0.x - lse;   // transposed: column u, index t
    if (have_label) lp_labelT[(b * UU + u) * TS + t] = lab_logit - lse;
  }
}

// ---------------- Kernel 2: anti-diagonal alpha recursion, 1 wave per batch ----
// Branch-free, DPP neighbor, conflict-free transposed LDS, prefetch depth 1.
__global__ __launch_bounds__(64) void alpha_dp(
    const float* __restrict__ lp_blankT, const float* __restrict__ lp_labelT,
    const int* __restrict__ logit_lens, const int* __restrict__ y_lens,
    float* __restrict__ losses) {
  const int b = blockIdx.x;
  const int lane = threadIdx.x;      // lane == u; lane 63 also owns u=64 via A64

  __shared__ float sb[U1 * TS];      // 34320 B
  __shared__ float sl[UU * TS];      // 33792 B
  {
    const float4* g1 = (const float4*)(lp_blankT + (size_t)b * U1 * TS);
    float4* s1 = (float4*)sb;
    for (int i = lane; i < U1 * TS / 4; i += 64) s1[i] = g1[i];
    const float4* g2 = (const float4*)(lp_labelT + (size_t)b * UU * TS);
    float4* s2 = (float4*)sl;
    for (int i = lane; i < UU * TS / 4; i += 64) s2[i] = g2[i];
  }
  __syncthreads();

  const int tEnd = logit_lens[b] - 1;   // in [63,127]
  const int uEnd = y_lens[b];           // in [32,64]
  const int dT = tEnd + uEnd;
  const int u = lane;
  const int lrow = (u >= 1 ? u - 1 : 0) * TS;   // label column base (u>=1 lanes)

  float A = NEGINF;        // alpha[d-u][u] after iteration d
  float A64 = NEGINF;      // lane 63: alpha[d-64][64]
  float result = 0.f;

  // address helpers (affine in d, clamped so always in-bounds)
  auto bofs  = [&](int d_) { int t_ = d_ - u;  int tc = min(max(t_, 1), 127); return u * TS + (tc - 1); };
  auto lofs  = [&](int d_) { int t_ = d_ - u;  int tc = min(max(t_, 0), 127); return lrow + tc; };
  auto b64ofs = [&](int d_) { int t_ = d_ - 64; int tc = min(max(t_, 1), 127); return 64 * TS + (tc - 1); };
  auto l64ofs = [&](int d_) { int t_ = d_ - 64; int tc = min(max(t_, 0), 127); return 63 * TS + tc; };

  float bv = sb[bofs(0)], lv = sl[lofs(0)];
  float b64v = sb[b64ofs(0)], l64v = sl[l64ofs(0)];

#pragma unroll 4
  for (int d = 0; d < TT + UU; ++d) {
    // prefetch next iteration's LDS values (independent of the alpha chain)
    const float bv_n   = sb[bofs(d + 1)];
    const float lv_n   = sl[lofs(d + 1)];
    const float b64v_n = sb[b64ofs(d + 1)];
    const float l64v_n = sl[l64ofs(d + 1)];

    const float a_left = shfl_up1(A);
    const int t = d - u;

    const float top = (t >= 1 && t <= 127) ? A + bv : NEGINF;
    const float lft = (u >= 1 && t >= 0 && t <= 127) ? a_left + lv : NEGINF;
    float v = lae(top, lft);
    if (t == 0 && u == 0) v = 0.f;                 // alpha[0][0]

    // u = 64 cell (uses PRE-update A; meaningful on lane 63 only)
    const int t64 = d - 64;
    const float top64 = (t64 >= 1) ? A64 + b64v : NEGINF;
    const float lft64 = (t64 >= 0) ? A + l64v : NEGINF;
    const float v64 = lae(top64, lft64);
    if (t64 >= 0) A64 = v64;

    A = v;

    if (d == dT) {
      if (u == uEnd) result = A + sb[u * TS + tEnd];
      if (uEnd == 64 && lane == 63) result = A64 + sb[64 * TS + tEnd];
    }

    bv = bv_n; lv = lv_n; b64v = b64v_n; l64v = l64v_n;
  }

  if (u == uEnd || (uEnd == 64 && lane == 63)) losses[b] = -result;
}

// ---------------- Kernel 3: mean over batch ----------------------------------
__global__ void finalize(const float* __restrict__ losses, float* __restrict__ out) {
  if (threadIdx.x == 0) {
    float s = 0.f;
#pragma unroll
    for (int i = 0; i < BB; ++i) s += losses[i];
    out[0] = s / (float)BB;
  }
}

extern "C" void kernel_launch(void* const* d_in, const int* in_sizes, int n_in,
                              void* d_out, int out_size, void* d_ws, size_t ws_size,
                              hipStream_t stream) {
  const float* logits     = (const float*)d_in[0];
  const int*   logit_lens = (const int*)d_in[1];
  const int*   y          = (const int*)d_in[2];
  const int*   y_lens     = (const int*)d_in[3];
  float* out = (float*)d_out;

  float* lp_blankT = (float*)d_ws;                        // BB*U1*TS floats
  float* lp_labelT = lp_blankT + BB * U1 * TS;            // BB*UU*TS floats
  float* losses    = lp_labelT + BB * UU * TS;            // BB floats

  const int rows = BB * TT * U1;                          // 66560
  lse_gather<<<rows / 4, 256, 0, stream>>>(logits, y, logit_lens, y_lens,
                                           lp_blankT, lp_labelT);
  alpha_dp<<<BB, 64, 0, stream>>>(lp_blankT, lp_labelT, logit_lens, y_lens, losses);
  finalize<<<1, 64, 0, stream>>>(losses, out);
}

// Round 3
// 53.686 us; speedup vs baseline: 3.6275x; 1.5383x over previous
//
#include <hip/hip_runtime.h>
#include <math.h>

#define BB 8
#define TT 128
#define U1 65
#define UU 64
#define VV 1024
#define CSTR 130            // comb row stride (pairs); 2-way-bank-conflict-free on DP reads
#define COMB_N 8456         // 65*130 = 8450 pairs + 6 pad (prefetch overrun headroom)
#define NEGINF -1e30f
#define LOG2E 1.4426950408889634f
#define LN2   0.6931471805599453f

// shfl_up by 1 via DPP wave_shr:1 (verified on HW in round 2; lane 0 gets old=0)
__device__ __forceinline__ float shfl_up1(float x) {
  return __int_as_float(__builtin_amdgcn_update_dpp(
      0, __float_as_int(x), 0x138, 0xf, 0xf, false));
}

// log-add-exp in log2 domain: native v_exp_f32 / v_log_f32, no ln2 muls
__device__ __forceinline__ float lae2(float a, float b) {
  const float mx = fmaxf(a, b);
  const float nd = fminf(a - b, b - a);     // -|a-b|
  return mx + log2f(1.f + exp2f(nd));
}

// ---------------- Kernel 1: logsumexp + fused comb-layout emit ---------------
// comb[b][u][t] = ( blank'[t-1][u],  label'[t][u-1] )  (log2-scaled)
// padding: comb[u][0].x = -inf (t=0 has no 'top'), comb[0][t].y = -inf (u=0 has no 'left')
__global__ __launch_bounds__(256) void lse_gather(
    const float* __restrict__ logits, const int* __restrict__ y,
    const int* __restrict__ logit_lens, const int* __restrict__ y_lens,
    float* __restrict__ comb) {     // float view of float2 pairs
  const int wave = threadIdx.x >> 6;
  const int lane = threadIdx.x & 63;
  const int row  = blockIdx.x * 4 + wave;          // row in [0, B*T*U1)
  const int u  = row % U1;
  const int bt = row / U1;
  const int b  = bt / TT;
  const int t  = bt % TT;

  float* cb = comb + (size_t)b * COMB_N * 2;

  // structural padding — writers are never-skipped waves (t=0, u=0 always valid)
  if (lane == 0) {
    if (t == 0) cb[2 * (u * CSTR) + 0] = NEGINF;           // comb[u][0].x
    if (u == 0) cb[2 * t + 1]          = NEGINF;           // comb[0][t].y
  }
  if (t >= logit_lens[b] || u > y_lens[b]) return;         // row not on any result path

  const float4* rp = (const float4*)(logits + (size_t)row * VV);
  float4 x0 = rp[lane];
  float4 x1 = rp[lane + 64];
  float4 x2 = rp[lane + 128];
  float4 x3 = rp[lane + 192];

  const bool have_label = (u < UU);
  float lab_logit = 0.f;
  if (have_label && lane == 0)
    lab_logit = logits[(size_t)row * VV + y[b * UU + u]];  // L1/L2 hit

  float m = fmaxf(fmaxf(fmaxf(x0.x, x0.y), fmaxf(x0.z, x0.w)),
                  fmaxf(fmaxf(x1.x, x1.y), fmaxf(x1.z, x1.w)));
  m = fmaxf(m, fmaxf(fmaxf(fmaxf(x2.x, x2.y), fmaxf(x2.z, x2.w)),
                     fmaxf(fmaxf(x3.x, x3.y), fmaxf(x3.z, x3.w))));
#pragma unroll
  for (int s = 32; s >= 1; s >>= 1) m = fmaxf(m, __shfl_xor(m, s));

  float ss = __expf(x0.x - m) + __expf(x0.y - m) + __expf(x0.z - m) + __expf(x0.w - m)
           + __expf(x1.x - m) + __expf(x1.y - m) + __expf(x1.z - m) + __expf(x1.w - m)
           + __expf(x2.x - m) + __expf(x2.y - m) + __expf(x2.z - m) + __expf(x2.w - m)
           + __expf(x3.x - m) + __expf(x3.y - m) + __expf(x3.z - m) + __expf(x3.w - m);
#pragma unroll
  for (int s = 32; s >= 1; s >>= 1) ss += __shfl_xor(ss, s);

  if (lane == 0) {
    const float lse = m + __logf(ss);
    cb[2 * (u * CSTR + t + 1) + 0] = (x0.x - lse) * LOG2E;         // blank -> comb[u][t+1].x
    if (have_label)
      cb[2 * ((u + 1) * CSTR + t) + 1] = (lab_logit - lse) * LOG2E; // label -> comb[u+1][t].y
  }
}

// ---------------- Kernel 2: anti-diagonal alpha recursion --------------------
// 256 threads stage comb (67.6 KB) to LDS; wave 0 runs the DP.
// Per diagonal d: read pair cs[129*u + d]; A = lae2(A + c.x, shfl_up(A) + c.y).
// Lane 63 additionally carries the u=64 cell via broadcast pair cs[8256 + d].
__global__ __launch_bounds__(256) void alpha_dp(
    const float2* __restrict__ comb, const int* __restrict__ logit_lens,
    const int* __restrict__ y_lens, float* __restrict__ losses) {
  const int b = blockIdx.x;
  const int tid = threadIdx.x;

  __shared__ __align__(16) float2 cs[COMB_N];
  {
    const float4* g = (const float4*)(comb + (size_t)b * COMB_N);
    float4* s = (float4*)cs;
    for (int i = tid; i < COMB_N / 2; i += 256) s[i] = g[i];
  }
  __syncthreads();
  if (tid >= 64) return;
  const int lane = tid;

  const int tEnd = logit_lens[b] - 1;   // in [63,127]
  const int uEnd = y_lens[b];           // in [32,64]
  const int dT   = tEnd + uEnd;         // >= 95

  const float2* cp   = cs + 129 * lane; // cp[d] = comb[u][d-u]
  const float2* cp64 = cs + 8256;       // cp64[d] = comb[64][d-64] (broadcast)

  float A   = (lane == 0) ? 0.f : NEGINF;   // alpha'[d-u][u] state (d=0)
  float A64 = NEGINF;                       // lane 63: alpha'[d-64][64]

#define STEP(cc, ee)                                      \
  {                                                       \
    const float aleft = shfl_up1(A);                      \
    const float top   = A + (cc).x;                       \
    const float lft   = aleft + (cc).y;                   \
    const float xt    = A64 + (ee).x;                     \
    const float xl    = A + (ee).y;   /* pre-update A */  \
    A   = lae2(top, lft);                                 \
    A64 = lae2(xt, xl);                                   \
  }

  // preload d = 1..4
  float2 c0 = cp[1], c1 = cp[2], c2 = cp[3], c3 = cp[4];
  float2 e0 = cp64[1], e1 = cp64[2], e2 = cp64[3], e3 = cp64[4];

  int d = 1;
  for (; d + 3 <= dT; d += 4) {
    const float2 n0 = cp[d + 4], n1 = cp[d + 5], n2 = cp[d + 6], n3 = cp[d + 7];
    const float2 f0 = cp64[d + 4], f1 = cp64[d + 5], f2 = cp64[d + 6], f3 = cp64[d + 7];
    STEP(c0, e0) STEP(c1, e1) STEP(c2, e2) STEP(c3, e3)
    c0 = n0; c1 = n1; c2 = n2; c3 = n3;
    e0 = f0; e1 = f1; e2 = f2; e3 = f3;
  }
  for (; d <= dT; ++d) {                  // <=3 tail iterations, direct reads
    const float2 c = cp[d], e = cp64[d];
    STEP(c, e)
  }
#undef STEP

  // result: alpha'[tEnd][uEnd] + blank'[tEnd][uEnd]  (blank' = comb[uEnd][tEnd+1].x)
  if (uEnd == 64) {
    if (lane == 63) losses[b] = -(A64 + cs[64 * CSTR + tEnd + 1].x) * LN2;
  } else {
    if (lane == uEnd) losses[b] = -(A + cs[uEnd * CSTR + tEnd + 1].x) * LN2;
  }
}

// ---------------- Kernel 3: mean over batch ----------------------------------
__global__ void finalize(const float* __restrict__ losses, float* __restrict__ out) {
  if (threadIdx.x == 0) {
    float s = 0.f;
#pragma unroll
    for (int i = 0; i < BB; ++i) s += losses[i];
    out[0] = s / (float)BB;
  }
}

extern "C" void kernel_launch(void* const* d_in, const int* in_sizes, int n_in,
                              void* d_out, int out_size, void* d_ws, size_t ws_size,
                              hipStream_t stream) {
  const float* logits     = (const float*)d_in[0];
  const int*   logit_lens = (const int*)d_in[1];
  const int*   y          = (const int*)d_in[2];
  const int*   y_lens     = (const int*)d_in[3];
  float* out = (float*)d_out;

  float2* comb  = (float2*)d_ws;                       // BB * COMB_N pairs
  float* losses = (float*)(comb + (size_t)BB * COMB_N);

  const int rows = BB * TT * U1;                       // 66560
  lse_gather<<<rows / 4, 256, 0, stream>>>(logits, y, logit_lens, y_lens, (float*)comb);
  alpha_dp<<<BB, 256, 0, stream>>>(comb, logit_lens, y_lens, losses);
  finalize<<<1, 64, 0, stream>>>(losses, out);
}